// Round 15
// baseline (636.687 us; speedup 1.0000x reference)
//
#include <hip/hip_runtime.h>
#include <hip/hip_bf16.h>
#include <cstdint>

// LSTM cell, B=16384, IN=512, H=512, fused 4-gate bf16 MFMA GEMM.
// Round 14b: 3 blocks/CU experiment, race-fixed. Ring-2 (48KB) with the
// minimum-2-phase sync: {STAGE(j+1); reads(j); lgk0; MFMA; vmcnt0; BAR}.
// (r14's NaN: per-wave vmcnt before reads, no barrier -> read other waves'
// un-retired DMA. The vmcnt(0)+BAR pair at iter end restores the r13
// all-waves-retired guarantee.)

typedef __attribute__((ext_vector_type(8))) __bf16 bf16x8;
typedef __attribute__((ext_vector_type(4))) float f32x4;
typedef __attribute__((address_space(3))) char lds_char;

#define GLOAD_LDS16(gp, lp)                                                        \
    __builtin_amdgcn_global_load_lds(                                              \
        (const __attribute__((address_space(1))) void*)(gp),                       \
        (__attribute__((address_space(3))) void*)(lp), 16, 0, 0)

#define BAR()  asm volatile("s_barrier" ::: "memory")
#define VMW0() asm volatile("s_waitcnt vmcnt(0)" ::: "memory")
#define LGK0() { asm volatile("s_waitcnt lgkmcnt(0)" ::: "memory");                \
                 __builtin_amdgcn_sched_barrier(0); }
#define DSR(dst, off)                                                              \
    asm volatile("ds_read_b128 %0, %1" : "=v"(dst) : "v"(lds3 + (off)))

__device__ __forceinline__ unsigned short f2bf(float f) {
    unsigned int u = __float_as_uint(f);
    u = (u + 0x7FFFu + ((u >> 16) & 1u)) >> 16;   // RNE
    return (unsigned short)u;
}
__device__ __forceinline__ float tanh_fast(float x) {
    float ax = fabsf(x);
    float e  = __expf(2.f * ax);
    float t  = 1.f - 2.f / (e + 1.f);
    return copysignf(t, x);
}

// ---------------- prepass A (verified, unchanged) ----------------
__global__ __launch_bounds__(256) void conv_a_kernel(const float* __restrict__ x,
                                                     const float* __restrict__ h,
                                                     unsigned short* __restrict__ A) {
    int G  = blockIdx.x * 256 + threadIdx.x;
    int b  = G >> 10;
    int p  = G & 1023;
    int mt = b >> 5;
    int kt = (b >> 1) & 15;
    int ks = b & 1;
    int row = p >> 2;
    int c   = (p & 3) ^ ((row >> 1) & 3);
    int r   = mt * 256 + row;
    int k0  = kt * 64 + ks * 32 + c * 8;
    const float* src = (k0 < 512) ? (x + (size_t)r * 512 + k0)
                                  : (h + (size_t)r * 512 + (k0 - 512));
    const float4* s4 = reinterpret_cast<const float4*>(src);
    float4 v0 = s4[0];
    float4 v1 = s4[1];
    uint4 o;
    o.x = (unsigned)f2bf(v0.x) | ((unsigned)f2bf(v0.y) << 16);
    o.y = (unsigned)f2bf(v0.z) | ((unsigned)f2bf(v0.w) << 16);
    o.z = (unsigned)f2bf(v1.x) | ((unsigned)f2bf(v1.y) << 16);
    o.w = (unsigned)f2bf(v1.z) | ((unsigned)f2bf(v1.w) << 16);
    *reinterpret_cast<uint4*>(A + ((size_t)b * 1024 + p) * 8) = o;
}

// ---------------- prepass B (verified, unchanged) ----------------
__global__ __launch_bounds__(256) void conv_w_kernel(const float* __restrict__ w0,
                                                     const float* __restrict__ w1,
                                                     const float* __restrict__ w2,
                                                     const float* __restrict__ w3,
                                                     unsigned short* __restrict__ Wt) {
    int G  = blockIdx.x * 256 + threadIdx.x;   // 262,144 chunks
    int b  = G >> 9;
    int p  = G & 511;
    int nb = b >> 5;
    int t  = b & 31;
    int col = p >> 2;
    int kc  = (p & 3) ^ ((col >> 1) & 3);
    int g   = col >> 5;
    int n   = nb * 32 + (col & 31);
    int k0  = t * 32 + kc * 8;
    const float* Wg = (g == 0) ? w0 : (g == 1) ? w1 : (g == 2) ? w2 : w3;
    unsigned short us[8];
    #pragma unroll
    for (int u = 0; u < 8; ++u) us[u] = f2bf(Wg[(size_t)(k0 + u) * 512 + n]);
    uint4 o;
    o.x = (unsigned)us[0] | ((unsigned)us[1] << 16);
    o.y = (unsigned)us[2] | ((unsigned)us[3] << 16);
    o.z = (unsigned)us[4] | ((unsigned)us[5] << 16);
    o.w = (unsigned)us[6] | ((unsigned)us[7] << 16);
    *reinterpret_cast<uint4*>(Wt + ((size_t)b * 512 + p) * 8) = o;
}

// ---------------- fused GEMM: 256x128 tile, ring-2, 3 blocks/CU ----------------
__global__ __launch_bounds__(512, 6) void lstm_gemm8(
    const char* __restrict__ Apre, const char* __restrict__ Bpre,
    const float* __restrict__ c_cur,
    const float* __restrict__ bi_p, const float* __restrict__ bf_p,
    const float* __restrict__ bo_p, const float* __restrict__ bc_p,
    float* __restrict__ h_out, float* __restrict__ c_out)
{
    extern __shared__ char smem[];
    lds_char* lds3 = (lds_char*)smem;
    const int tid  = threadIdx.x;
    const int lane = tid & 63;
    const int wid  = tid >> 6;    // 0..7
    const int wm   = wid >> 1;    // 0..3 (64-row group)
    const int wn   = wid & 1;     // 0..1 (16-h half)

    // XCD-grouped bijective mapping (r13, FETCH-verified)
    const int mt = (blockIdx.x & 7) * 8 + (blockIdx.x >> 7);
    const int nb = (blockIdx.x >> 3) & 15;

    const int ar    = lane & 15;
    const int swz   = ((lane >> 4) ^ ((ar >> 1) & 3)) << 4;
    const int aoffb = ar * 64 + swz;
    const int boffb = 16384 + (wn * 16 + ar) * 64 + swz;
    const int swl   = wid * 1024;

    const char* ApreB = Apre + (((size_t)mt * 32) << 14) + (size_t)tid * 16;
    const char* BpreB = Bpre + (((size_t)nb * 32) << 13) + (size_t)tid * 16;

    // stage K-tile t into ring buffer bb: A 16KB (2 loads) + B 8KB (1 load)
#define STAGE(t, bb) {                                                  \
        const char* ga_ = ApreB + (((size_t)(t)) << 14);                \
        const char* gb_ = BpreB + (((size_t)(t)) << 13);                \
        GLOAD_LDS16(ga_,        smem + (bb) + swl);                     \
        GLOAD_LDS16(ga_ + 8192, smem + (bb) + 8192 + swl);              \
        GLOAD_LDS16(gb_,        smem + (bb) + 16384 + swl); }

    f32x4 acc[4][4];   // [gate][m-frag]
    #pragma unroll
    for (int g = 0; g < 4; ++g)
        #pragma unroll
        for (int m = 0; m < 4; ++m)
            acc[g][m] = (f32x4){0.f, 0.f, 0.f, 0.f};

    bf16x8 aFr[4], bFr[4];

    // prologue: stage K-tile 0 into buf0; all waves' DMA retired before reads
    STAGE(0, 0);
    VMW0();
    BAR();

    #pragma unroll 1
    for (int j = 0; j < 32; ++j) {
        const int buf  = (j & 1) * 24576;
        const int nbuf = buf ^ 24576;

        // issue next tile's staging first (latency hides under reads+MFMA);
        // nbuf held tile j-1, fully read by all waves before iter j-1's BAR.
        if (j < 31) STAGE(j + 1, nbuf);

        // fragment reads of tile j (all waves' tile-j DMA retired: iter j-1's
        // VMW0+BAR — or the prologue's for j=0)
        #pragma unroll
        for (int mi = 0; mi < 4; ++mi)
            DSR(aFr[mi], buf + wm * 4096 + mi * 1024 + aoffb);
        #pragma unroll
        for (int g = 0; g < 4; ++g)
            DSR(bFr[g], buf + g * 2048 + boffb);

        LGK0();
        __builtin_amdgcn_s_setprio(1);
        #pragma unroll
        for (int g = 0; g < 4; ++g)
            #pragma unroll
            for (int m = 0; m < 4; ++m)
                acc[g][m] = __builtin_amdgcn_mfma_f32_16x16x32_bf16(
                    aFr[m], bFr[g], acc[g][m], 0, 0, 0);
        __builtin_amdgcn_s_setprio(0);

        if (j < 31) VMW0();   // this wave's tile-(j+1) DMA retired
        BAR();                // -> all waves retired: reads in iter j+1 safe
    }

    // fused LSTM epilogue (verified): all 4 gates in-lane
    const int r4   = (lane >> 4) * 4;
    const int hcol = nb * 32 + wn * 16 + ar;
    const float bii = bi_p[hcol], bff = bf_p[hcol];
    const float boo = bo_p[hcol], bcc = bc_p[hcol];
    #pragma unroll
    for (int m = 0; m < 4; ++m) {
        const int rowb = mt * 256 + wm * 64 + m * 16 + r4;
        #pragma unroll
        for (int rr = 0; rr < 4; ++rr) {
            const size_t o = (size_t)(rowb + rr) * 512 + hcol;
            float gi = acc[0][m][rr] + bii;
            float gf = acc[1][m][rr] + bff;
            float go = acc[2][m][rr] + boo;
            float gc = acc[3][m][rr] + bcc;
            float is = 1.f / (1.f + __expf(-gi));
            float fs = 1.f / (1.f + __expf(-gf));
            float os = 1.f / (1.f + __expf(-go));
            float ct = tanh_fast(gc);
            float cn = fs * c_cur[o] + is * ct;
            h_out[o] = os * tanh_fast(cn);
            c_out[o] = cn;
        }
    }
#undef STAGE
}

extern "C" void kernel_launch(void* const* d_in, const int* in_sizes, int n_in,
                              void* d_out, int out_size, void* d_ws, size_t ws_size,
                              hipStream_t stream) {
    const float* x   = (const float*)d_in[0];
    const float* h   = (const float*)d_in[1];
    const float* c   = (const float*)d_in[2];
    const float* W_i = (const float*)d_in[3];
    const float* b_i = (const float*)d_in[4];
    const float* W_f = (const float*)d_in[5];
    const float* b_f = (const float*)d_in[6];
    const float* W_o = (const float*)d_in[7];
    const float* b_o = (const float*)d_in[8];
    const float* W_c = (const float*)d_in[9];
    const float* b_c = (const float*)d_in[10];

    unsigned short* Apre = (unsigned short*)d_ws;                      // 33,554,432 B
    unsigned short* Bpre = (unsigned short*)((char*)d_ws + 33554432);  //  4,194,304 B

    float* h_out = (float*)d_out;
    float* c_out = h_out + (size_t)16384 * 512;

    (void)hipFuncSetAttribute(reinterpret_cast<const void*>(lstm_gemm8),
                              hipFuncAttributeMaxDynamicSharedMemorySize, 49152);

    conv_a_kernel<<<8192, 256, 0, stream>>>(x, h, Apre);
    conv_w_kernel<<<1024, 256, 0, stream>>>(W_i, W_f, W_o, W_c, Bpre);
    lstm_gemm8<<<1024, 512, 49152, stream>>>((const char*)Apre, (const char*)Bpre,
                                             c, b_i, b_f, b_o, b_c, h_out, c_out);
}

// Round 16
// 100.690 us; speedup vs baseline: 6.3232x; 6.3232x over previous
//
#include <hip/hip_runtime.h>
#include <hip/hip_bf16.h>
#include <cstdint>

// LSTM cell, B=16384, IN=512, H=512, fused 4-gate bf16 MFMA GEMM.
// Round 16: r13 (256x128 tile, ring-3, 2 blocks/CU, XCD-grouped mapping)
// + counted-lgkmcnt batched read/MFMA interleave (reads A0,B0,B1,A1,B2,B3,
// A2,A3; MFMA groups behind lgkmcnt(6/5/4/2/0)). Sync structure unchanged.

typedef __attribute__((ext_vector_type(8))) __bf16 bf16x8;
typedef __attribute__((ext_vector_type(4))) float f32x4;
typedef __attribute__((address_space(3))) char lds_char;

#define GLOAD_LDS16(gp, lp)                                                        \
    __builtin_amdgcn_global_load_lds(                                              \
        (const __attribute__((address_space(1))) void*)(gp),                       \
        (__attribute__((address_space(3))) void*)(lp), 16, 0, 0)

#define BAR()  asm volatile("s_barrier" ::: "memory")
#define VMW3() asm volatile("s_waitcnt vmcnt(3)" ::: "memory")
#define VMW0() asm volatile("s_waitcnt vmcnt(0)" ::: "memory")
#define LGK(n) { asm volatile("s_waitcnt lgkmcnt(" #n ")" ::: "memory");           \
                 __builtin_amdgcn_sched_barrier(0); }
#define DSR(dst, off)                                                              \
    asm volatile("ds_read_b128 %0, %1" : "=v"(dst) : "v"(lds3 + (off)))

__device__ __forceinline__ unsigned short f2bf(float f) {
    unsigned int u = __float_as_uint(f);
    u = (u + 0x7FFFu + ((u >> 16) & 1u)) >> 16;   // RNE
    return (unsigned short)u;
}
__device__ __forceinline__ float tanh_fast(float x) {
    float ax = fabsf(x);
    float e  = __expf(2.f * ax);
    float t  = 1.f - 2.f / (e + 1.f);
    return copysignf(t, x);
}

// ---------------- prepass A (verified, unchanged) ----------------
__global__ __launch_bounds__(256) void conv_a_kernel(const float* __restrict__ x,
                                                     const float* __restrict__ h,
                                                     unsigned short* __restrict__ A) {
    int G  = blockIdx.x * 256 + threadIdx.x;
    int b  = G >> 10;
    int p  = G & 1023;
    int mt = b >> 5;
    int kt = (b >> 1) & 15;
    int ks = b & 1;
    int row = p >> 2;
    int c   = (p & 3) ^ ((row >> 1) & 3);
    int r   = mt * 256 + row;
    int k0  = kt * 64 + ks * 32 + c * 8;
    const float* src = (k0 < 512) ? (x + (size_t)r * 512 + k0)
                                  : (h + (size_t)r * 512 + (k0 - 512));
    const float4* s4 = reinterpret_cast<const float4*>(src);
    float4 v0 = s4[0];
    float4 v1 = s4[1];
    uint4 o;
    o.x = (unsigned)f2bf(v0.x) | ((unsigned)f2bf(v0.y) << 16);
    o.y = (unsigned)f2bf(v0.z) | ((unsigned)f2bf(v0.w) << 16);
    o.z = (unsigned)f2bf(v1.x) | ((unsigned)f2bf(v1.y) << 16);
    o.w = (unsigned)f2bf(v1.z) | ((unsigned)f2bf(v1.w) << 16);
    *reinterpret_cast<uint4*>(A + ((size_t)b * 1024 + p) * 8) = o;
}

// ---------------- prepass B (verified, unchanged) ----------------
__global__ __launch_bounds__(256) void conv_w_kernel(const float* __restrict__ w0,
                                                     const float* __restrict__ w1,
                                                     const float* __restrict__ w2,
                                                     const float* __restrict__ w3,
                                                     unsigned short* __restrict__ Wt) {
    int G  = blockIdx.x * 256 + threadIdx.x;   // 262,144 chunks
    int b  = G >> 9;
    int p  = G & 511;
    int nb = b >> 5;
    int t  = b & 31;
    int col = p >> 2;
    int kc  = (p & 3) ^ ((col >> 1) & 3);
    int g   = col >> 5;
    int n   = nb * 32 + (col & 31);
    int k0  = t * 32 + kc * 8;
    const float* Wg = (g == 0) ? w0 : (g == 1) ? w1 : (g == 2) ? w2 : w3;
    unsigned short us[8];
    #pragma unroll
    for (int u = 0; u < 8; ++u) us[u] = f2bf(Wg[(size_t)(k0 + u) * 512 + n]);
    uint4 o;
    o.x = (unsigned)us[0] | ((unsigned)us[1] << 16);
    o.y = (unsigned)us[2] | ((unsigned)us[3] << 16);
    o.z = (unsigned)us[4] | ((unsigned)us[5] << 16);
    o.w = (unsigned)us[6] | ((unsigned)us[7] << 16);
    *reinterpret_cast<uint4*>(Wt + ((size_t)b * 512 + p) * 8) = o;
}

// ---------------- fused GEMM: 256x128 tile, ring-3, 2 blocks/CU ----------------
__global__ __launch_bounds__(512, 4) void lstm_gemm8(
    const char* __restrict__ Apre, const char* __restrict__ Bpre,
    const float* __restrict__ c_cur,
    const float* __restrict__ bi_p, const float* __restrict__ bf_p,
    const float* __restrict__ bo_p, const float* __restrict__ bc_p,
    float* __restrict__ h_out, float* __restrict__ c_out)
{
    extern __shared__ char smem[];
    lds_char* lds3 = (lds_char*)smem;
    const int tid  = threadIdx.x;
    const int lane = tid & 63;
    const int wid  = tid >> 6;    // 0..7
    const int wm   = wid >> 1;    // 0..3 (64-row group)
    const int wn   = wid & 1;     // 0..1 (16-h half)

    // XCD-grouped bijective mapping (r13, FETCH-verified)
    const int mt = (blockIdx.x & 7) * 8 + (blockIdx.x >> 7);
    const int nb = (blockIdx.x >> 3) & 15;

    const int ar    = lane & 15;
    const int swz   = ((lane >> 4) ^ ((ar >> 1) & 3)) << 4;
    const int aoffb = ar * 64 + swz;
    const int boffb = 16384 + (wn * 16 + ar) * 64 + swz;
    const int swl   = wid * 1024;

    const char* ApreB = Apre + (((size_t)mt * 32) << 14) + (size_t)tid * 16;
    const char* BpreB = Bpre + (((size_t)nb * 32) << 13) + (size_t)tid * 16;

    // stage K-tile t into ring buffer bb: A 16KB (2 loads) + B 8KB (1 load)
#define STAGE(t, bb) {                                                  \
        const char* ga_ = ApreB + (((size_t)(t)) << 14);                \
        const char* gb_ = BpreB + (((size_t)(t)) << 13);                \
        GLOAD_LDS16(ga_,        smem + (bb) + swl);                     \
        GLOAD_LDS16(ga_ + 8192, smem + (bb) + 8192 + swl);              \
        GLOAD_LDS16(gb_,        smem + (bb) + 16384 + swl); }

    f32x4 acc[4][4];   // [gate][m-frag]
    #pragma unroll
    for (int g = 0; g < 4; ++g)
        #pragma unroll
        for (int m = 0; m < 4; ++m)
            acc[g][m] = (f32x4){0.f, 0.f, 0.f, 0.f};

    bf16x8 aFr[4], bFr[4];

#define MM1(m, g) acc[g][m] = __builtin_amdgcn_mfma_f32_16x16x32_bf16(   \
                      aFr[m], bFr[g], acc[g][m], 0, 0, 0);

    // prologue: stage K-tiles 0,1 into bufs 0,1 (6 loads in flight)
    STAGE(0, 0);
    STAGE(1, 24576);

    #pragma unroll 1
    for (int j = 0; j < 32; ++j) {
        const int buf  = (j % 3) * 24576;
        const int bufN = ((j + 2) % 3) * 24576;

        if (j < 31) { VMW3(); } else { VMW0(); }
        BAR();
        // stage j+2 into buf((j+2)%3) == buf(j-1): safe, all reads of j-1
        // retired before this barrier (lgkmcnt drained in iter j-1).
        if (j < 30) STAGE(j + 2, bufN);

        const int ab = buf + wm * 4096 + aoffb;
        // reads ordered for earliest MFMA start
        DSR(aFr[0], ab);
        DSR(bFr[0], buf + boffb);
        DSR(bFr[1], buf + 2048 + boffb);
        DSR(aFr[1], ab + 1024);
        DSR(bFr[2], buf + 4096 + boffb);
        DSR(bFr[3], buf + 6144 + boffb);
        DSR(aFr[2], ab + 2048);
        DSR(aFr[3], ab + 3072);

        __builtin_amdgcn_s_setprio(1);
        LGK(6);   // A0,B0 ready
        MM1(0, 0)
        LGK(5);   // B1
        MM1(0, 1)
        LGK(4);   // A1
        MM1(1, 0) MM1(1, 1)
        LGK(2);   // B2,B3
        MM1(0, 2) MM1(0, 3) MM1(1, 2) MM1(1, 3)
        LGK(0);   // A2,A3
        MM1(2, 0) MM1(2, 1) MM1(2, 2) MM1(2, 3)
        MM1(3, 0) MM1(3, 1) MM1(3, 2) MM1(3, 3)
        __builtin_amdgcn_s_setprio(0);
    }

    // fused LSTM epilogue (verified): all 4 gates in-lane
    const int r4   = (lane >> 4) * 4;
    const int hcol = nb * 32 + wn * 16 + ar;
    const float bii = bi_p[hcol], bff = bf_p[hcol];
    const float boo = bo_p[hcol], bcc = bc_p[hcol];
    #pragma unroll
    for (int m = 0; m < 4; ++m) {
        const int rowb = mt * 256 + wm * 64 + m * 16 + r4;
        #pragma unroll
        for (int rr = 0; rr < 4; ++rr) {
            const size_t o = (size_t)(rowb + rr) * 512 + hcol;
            float gi = acc[0][m][rr] + bii;
            float gf = acc[1][m][rr] + bff;
            float go = acc[2][m][rr] + boo;
            float gc = acc[3][m][rr] + bcc;
            float is = 1.f / (1.f + __expf(-gi));
            float fs = 1.f / (1.f + __expf(-gf));
            float os = 1.f / (1.f + __expf(-go));
            float ct = tanh_fast(gc);
            float cn = fs * c_cur[o] + is * ct;
            h_out[o] = os * tanh_fast(cn);
            c_out[o] = cn;
        }
    }
#undef STAGE
#undef MM1
}

extern "C" void kernel_launch(void* const* d_in, const int* in_sizes, int n_in,
                              void* d_out, int out_size, void* d_ws, size_t ws_size,
                              hipStream_t stream) {
    const float* x   = (const float*)d_in[0];
    const float* h   = (const float*)d_in[1];
    const float* c   = (const float*)d_in[2];
    const float* W_i = (const float*)d_in[3];
    const float* b_i = (const float*)d_in[4];
    const float* W_f = (const float*)d_in[5];
    const float* b_f = (const float*)d_in[6];
    const float* W_o = (const float*)d_in[7];
    const float* b_o = (const float*)d_in[8];
    const float* W_c = (const float*)d_in[9];
    const float* b_c = (const float*)d_in[10];

    unsigned short* Apre = (unsigned short*)d_ws;                      // 33,554,432 B
    unsigned short* Bpre = (unsigned short*)((char*)d_ws + 33554432);  //  4,194,304 B

    float* h_out = (float*)d_out;
    float* c_out = h_out + (size_t)16384 * 512;

    (void)hipFuncSetAttribute(reinterpret_cast<const void*>(lstm_gemm8),
                              hipFuncAttributeMaxDynamicSharedMemorySize, 73728);

    conv_a_kernel<<<8192, 256, 0, stream>>>(x, h, Apre);
    conv_w_kernel<<<1024, 256, 0, stream>>>(W_i, W_f, W_o, W_c, Bpre);
    lstm_gemm8<<<1024, 512, 73728, stream>>>((const char*)Apre, (const char*)Bpre,
                                             c, b_i, b_f, b_o, b_c, h_out, c_out);
}

// Round 17
// 85.566 us; speedup vs baseline: 7.4409x; 1.1768x over previous
//
#include <hip/hip_runtime.h>
#include <hip/hip_bf16.h>
#include <cstdint>

// LSTM cell, B=16384, IN=512, H=512 — fused 4-gate INT8 MFMA GEMM.
// Round 17: i8 path. A: per-row scale s_i; W: per-(gate,col) scale t_gn;
// gate = (float)i32dot * s_i * t_gn + bias (dequant exact, i32 accum exact).
// GEMM geometry/sync = r13 verified template (256x128 tile, ring-3, vmcnt(3),
// 2 blocks/CU, XCD-grouped mapping), BK=64, mfma_i32_16x16x64_i8, 16 K-iters.

typedef __attribute__((ext_vector_type(4))) int   i32x4;
typedef __attribute__((ext_vector_type(4))) float f32x4;
typedef __attribute__((address_space(3))) char lds_char;

#define GLOAD_LDS16(gp, lp)                                                        \
    __builtin_amdgcn_global_load_lds(                                              \
        (const __attribute__((address_space(1))) void*)(gp),                       \
        (__attribute__((address_space(3))) void*)(lp), 16, 0, 0)

#define BAR()  asm volatile("s_barrier" ::: "memory")
#define VMW3() asm volatile("s_waitcnt vmcnt(3)" ::: "memory")
#define VMW0() asm volatile("s_waitcnt vmcnt(0)" ::: "memory")
#define LGK0() { asm volatile("s_waitcnt lgkmcnt(0)" ::: "memory");                \
                 __builtin_amdgcn_sched_barrier(0); }
#define DSR(dst, off)                                                              \
    asm volatile("ds_read_b128 %0, %1" : "=v"(dst) : "v"(lds3 + (off)))

__device__ __forceinline__ float tanh_fast(float x) {
    float ax = fabsf(x);
    float e  = __expf(2.f * ax);
    float t  = 1.f - 2.f / (e + 1.f);
    return copysignf(t, x);
}
__device__ __forceinline__ unsigned int pkq4(float a, float b, float c, float d,
                                             float qs) {
    int q0 = __float2int_rn(a * qs) & 255;
    int q1 = __float2int_rn(b * qs) & 255;
    int q2 = __float2int_rn(c * qs) & 255;
    int q3 = __float2int_rn(d * qs) & 255;
    return (unsigned)q0 | ((unsigned)q1 << 8) | ((unsigned)q2 << 16)
         | ((unsigned)q3 << 24);
}

// ---------------- prepass A: per-row max + quantize + swizzled layout ----------
// Aq: [mt=64][t=16] 16KB slices; position (row_local, kc_pos): 16B = 16 i8 of
// source k-chunk kc_src = kc_pos ^ ((row_local>>1)&3), k = t*64 + kc_src*16.
// One wave per row; lane covers k = lane*16 .. +16 (x for lane<32, h else).
__global__ __launch_bounds__(256) void conv_a_q(const float* __restrict__ x,
                                                const float* __restrict__ h,
                                                char* __restrict__ Aq,
                                                float* __restrict__ As) {
    const int lane = threadIdx.x & 63;
    const int r    = blockIdx.x * 4 + (threadIdx.x >> 6);   // grid 4096
    const int k0   = lane * 16;
    const float* src = (k0 < 512) ? (x + (size_t)r * 512 + k0)
                                  : (h + (size_t)r * 512 + (k0 - 512));
    const float4* s4 = reinterpret_cast<const float4*>(src);
    float4 v0 = s4[0], v1 = s4[1], v2 = s4[2], v3 = s4[3];

    float m = fabsf(v0.x);
    m = fmaxf(m, fabsf(v0.y)); m = fmaxf(m, fabsf(v0.z)); m = fmaxf(m, fabsf(v0.w));
    m = fmaxf(m, fabsf(v1.x)); m = fmaxf(m, fabsf(v1.y)); m = fmaxf(m, fabsf(v1.z));
    m = fmaxf(m, fabsf(v1.w)); m = fmaxf(m, fabsf(v2.x)); m = fmaxf(m, fabsf(v2.y));
    m = fmaxf(m, fabsf(v2.z)); m = fmaxf(m, fabsf(v2.w)); m = fmaxf(m, fabsf(v3.x));
    m = fmaxf(m, fabsf(v3.y)); m = fmaxf(m, fabsf(v3.z)); m = fmaxf(m, fabsf(v3.w));
    #pragma unroll
    for (int off = 1; off < 64; off <<= 1)
        m = fmaxf(m, __shfl_xor(m, off));
    m = fmaxf(m, 1e-20f);
    const float qs = 127.0f / m;
    if (lane == 0) As[r] = m * (1.0f / 127.0f);

    uint4 o;
    o.x = pkq4(v0.x, v0.y, v0.z, v0.w, qs);
    o.y = pkq4(v1.x, v1.y, v1.z, v1.w, qs);
    o.z = pkq4(v2.x, v2.y, v2.z, v2.w, qs);
    o.w = pkq4(v3.x, v3.y, v3.z, v3.w, qs);

    const int t     = lane >> 2;
    const int csrc  = lane & 3;
    const int mt    = r >> 8;
    const int rl    = r & 255;
    const int kcpos = csrc ^ ((rl >> 1) & 3);
    *reinterpret_cast<uint4*>(Aq + (((size_t)(mt * 16 + t)) << 14)
                                 + rl * 64 + kcpos * 16) = o;
}

// ---------------- prepass W pass 1: per-(gate,col) max ----------------
__global__ __launch_bounds__(256) void conv_w_max(const float* __restrict__ w0,
                                                  const float* __restrict__ w1,
                                                  const float* __restrict__ w2,
                                                  const float* __restrict__ w3,
                                                  float* __restrict__ Ws) {
    const int lane = threadIdx.x & 63;
    const int idx  = blockIdx.x * 4 + (threadIdx.x >> 6);   // grid 512 -> 0..2047
    const int g    = idx >> 9;
    const int n    = idx & 511;
    const float* Wg = (g == 0) ? w0 : (g == 1) ? w1 : (g == 2) ? w2 : w3;
    float m = 0.f;
    #pragma unroll
    for (int u = 0; u < 16; ++u)
        m = fmaxf(m, fabsf(Wg[(size_t)(lane * 16 + u) * 512 + n]));
    #pragma unroll
    for (int off = 1; off < 64; off <<= 1)
        m = fmaxf(m, __shfl_xor(m, off));
    if (lane == 0) Ws[idx] = fmaxf(m, 1e-20f) * (1.0f / 127.0f);
}

// ---------------- prepass W pass 2: quantize + swizzled layout ----------------
// Bq: [nb=16][t=16] 8KB slices; position (col 0..127, kc_pos): source
// kc_src = kc_pos ^ ((col>>1)&3); col = g*32+hl; n = nb*32+hl;
// data = i8(W_g[t*64 + kc_src*16 + u][n] / s), u=0..15.
__global__ __launch_bounds__(256) void conv_w_q(const float* __restrict__ w0,
                                                const float* __restrict__ w1,
                                                const float* __restrict__ w2,
                                                const float* __restrict__ w3,
                                                const float* __restrict__ Ws,
                                                char* __restrict__ Bq) {
    const int G  = blockIdx.x * 256 + threadIdx.x;   // grid 512 -> 131072
    const int b  = G >> 9;     // slice 0..255 = nb*16 + t
    const int p  = G & 511;
    const int nb = b >> 4;
    const int t  = b & 15;
    const int col   = p >> 2;
    const int kcpos = p & 3;
    const int kcsrc = kcpos ^ ((col >> 1) & 3);
    const int g  = col >> 5;
    const int n  = nb * 32 + (col & 31);
    const int k0 = t * 64 + kcsrc * 16;
    const float* Wg = (g == 0) ? w0 : (g == 1) ? w1 : (g == 2) ? w2 : w3;
    const float qs = 1.0f / Ws[g * 512 + n];
    float v[16];
    #pragma unroll
    for (int u = 0; u < 16; ++u) v[u] = Wg[(size_t)(k0 + u) * 512 + n];
    uint4 o;
    o.x = pkq4(v[0],  v[1],  v[2],  v[3],  qs);
    o.y = pkq4(v[4],  v[5],  v[6],  v[7],  qs);
    o.z = pkq4(v[8],  v[9],  v[10], v[11], qs);
    o.w = pkq4(v[12], v[13], v[14], v[15], qs);
    *reinterpret_cast<uint4*>(Bq + (size_t)b * 8192 + (size_t)p * 16) = o;
}

// ---------------- fused i8 GEMM: 256x128 tile, ring-3, 2 blocks/CU ----------------
__global__ __launch_bounds__(512, 4) void lstm_gemm8(
    const char* __restrict__ Aq, const char* __restrict__ Bq,
    const float* __restrict__ As, const float* __restrict__ Ws,
    const float* __restrict__ c_cur,
    const float* __restrict__ bi_p, const float* __restrict__ bf_p,
    const float* __restrict__ bo_p, const float* __restrict__ bc_p,
    float* __restrict__ h_out, float* __restrict__ c_out)
{
    extern __shared__ char smem[];
    lds_char* lds3 = (lds_char*)smem;
    const int tid  = threadIdx.x;
    const int lane = tid & 63;
    const int wid  = tid >> 6;    // 0..7
    const int wm   = wid >> 1;    // 0..3 (64-row group)
    const int wn   = wid & 1;     // 0..1 (16-h half)

    // XCD-grouped bijective mapping (r13, FETCH-verified)
    const int mt = (blockIdx.x & 7) * 8 + (blockIdx.x >> 7);
    const int nb = (blockIdx.x >> 3) & 15;

    const int ar    = lane & 15;
    const int swz   = ((lane >> 4) ^ ((ar >> 1) & 3)) << 4;
    const int aoffb = ar * 64 + swz;
    const int boffb = 16384 + (wn * 16 + ar) * 64 + swz;
    const int swl   = wid * 1024;

    const char* AqB = Aq + (((size_t)mt * 16) << 14) + (size_t)tid * 16;
    const char* BqB = Bq + (((size_t)nb * 16) << 13) + (size_t)tid * 16;

    // stage K-tile t (BK=64): A 16KB (2 loads) + B 8KB (1 load)
#define STAGE(t, bb) {                                                  \
        const char* ga_ = AqB + (((size_t)(t)) << 14);                  \
        const char* gb_ = BqB + (((size_t)(t)) << 13);                  \
        GLOAD_LDS16(ga_,        smem + (bb) + swl);                     \
        GLOAD_LDS16(ga_ + 8192, smem + (bb) + 8192 + swl);              \
        GLOAD_LDS16(gb_,        smem + (bb) + 16384 + swl); }

    i32x4 acc[4][4];   // [gate][m-frag]
    #pragma unroll
    for (int g = 0; g < 4; ++g)
        #pragma unroll
        for (int m = 0; m < 4; ++m)
            acc[g][m] = (i32x4){0, 0, 0, 0};

    i32x4 aFr[4], bFr[4];

    // prologue: stage K-tiles 0,1 into bufs 0,1 (6 loads in flight)
    STAGE(0, 0);
    STAGE(1, 24576);

    #pragma unroll 1
    for (int j = 0; j < 16; ++j) {
        const int buf  = (j % 3) * 24576;
        const int bufN = ((j + 2) % 3) * 24576;

        if (j < 15) { VMW3(); } else { VMW0(); }
        BAR();
        if (j < 14) STAGE(j + 2, bufN);

        #pragma unroll
        for (int mi = 0; mi < 4; ++mi)
            DSR(aFr[mi], buf + wm * 4096 + mi * 1024 + aoffb);
        #pragma unroll
        for (int g = 0; g < 4; ++g)
            DSR(bFr[g], buf + g * 2048 + boffb);

        LGK0();
        __builtin_amdgcn_s_setprio(1);
        #pragma unroll
        for (int g = 0; g < 4; ++g)
            #pragma unroll
            for (int m = 0; m < 4; ++m)
                acc[g][m] = __builtin_amdgcn_mfma_i32_16x16x64_i8(
                    aFr[m], bFr[g], acc[g][m], 0, 0, 0);
        __builtin_amdgcn_s_setprio(0);
    }

    // fused LSTM epilogue: dequant (s_i * t_gn) + gates, all in-lane
    const int r4   = (lane >> 4) * 4;
    const int hcol = nb * 32 + wn * 16 + ar;
    const float bii = bi_p[hcol], bff = bf_p[hcol];
    const float boo = bo_p[hcol], bcc = bc_p[hcol];
    const float sw0 = Ws[hcol],        sw1 = Ws[512 + hcol];
    const float sw2 = Ws[1024 + hcol], sw3 = Ws[1536 + hcol];
    #pragma unroll
    for (int m = 0; m < 4; ++m) {
        const int rowb = mt * 256 + wm * 64 + m * 16 + r4;
        const float4 sa = *reinterpret_cast<const float4*>(As + rowb);
        const float sar[4] = {sa.x, sa.y, sa.z, sa.w};
        #pragma unroll
        for (int rr = 0; rr < 4; ++rr) {
            const size_t o = (size_t)(rowb + rr) * 512 + hcol;
            const float s = sar[rr];
            float gi = (float)acc[0][m][rr] * (s * sw0) + bii;
            float gf = (float)acc[1][m][rr] * (s * sw1) + bff;
            float go = (float)acc[2][m][rr] * (s * sw2) + boo;
            float gc = (float)acc[3][m][rr] * (s * sw3) + bcc;
            float is = 1.f / (1.f + __expf(-gi));
            float fs = 1.f / (1.f + __expf(-gf));
            float os = 1.f / (1.f + __expf(-go));
            float ct = tanh_fast(gc);
            float cn = fs * c_cur[o] + is * ct;
            h_out[o] = os * tanh_fast(cn);
            c_out[o] = cn;
        }
    }
#undef STAGE
}

extern "C" void kernel_launch(void* const* d_in, const int* in_sizes, int n_in,
                              void* d_out, int out_size, void* d_ws, size_t ws_size,
                              hipStream_t stream) {
    const float* x   = (const float*)d_in[0];
    const float* h   = (const float*)d_in[1];
    const float* c   = (const float*)d_in[2];
    const float* W_i = (const float*)d_in[3];
    const float* b_i = (const float*)d_in[4];
    const float* W_f = (const float*)d_in[5];
    const float* b_f = (const float*)d_in[6];
    const float* W_o = (const float*)d_in[7];
    const float* b_o = (const float*)d_in[8];
    const float* W_c = (const float*)d_in[9];
    const float* b_c = (const float*)d_in[10];

    char*  Aq = (char*)d_ws;                             // 16,777,216 B
    char*  Bq = (char*)d_ws + 16777216;                  //  2,097,152 B
    float* As = (float*)((char*)d_ws + 18874368);        //     65,536 B
    float* Ws = (float*)((char*)d_ws + 18939904);        //      8,192 B

    float* h_out = (float*)d_out;
    float* c_out = h_out + (size_t)16384 * 512;

    (void)hipFuncSetAttribute(reinterpret_cast<const void*>(lstm_gemm8),
                              hipFuncAttributeMaxDynamicSharedMemorySize, 73728);

    conv_a_q<<<4096, 256, 0, stream>>>(x, h, Aq, As);
    conv_w_max<<<512, 256, 0, stream>>>(W_i, W_f, W_o, W_c, Ws);
    conv_w_q<<<512, 256, 0, stream>>>(W_i, W_f, W_o, W_c, Ws, Bq);
    lstm_gemm8<<<1024, 512, 73728, stream>>>(Aq, Bq, As, Ws, c,
                                             b_i, b_f, b_o, b_c, h_out, c_out);
}

// Round 18
// 76.546 us; speedup vs baseline: 8.3177x; 1.1178x over previous
//
#include <hip/hip_runtime.h>
#include <hip/hip_bf16.h>
#include <cstdint>

// LSTM cell, B=16384, IN=512, H=512 — fused 4-gate INT8 MFMA GEMM.
// Round 18: r17 GEMM/prepasses unchanged; epilogue rewritten division-free:
// sigma(x) = v_rcp(1 + exp2(-L*x)), tanh(x) = 2*v_rcp(1 + exp2(-2L*x)) - 1,
// with -L/-2L scales folded into dequant FMA constants. (No fast-math in the
// harness, so 1.f/x was a ~10-op v_div chain -> 5x per element; VALUBusy 42%.)

typedef __attribute__((ext_vector_type(4))) int   i32x4;
typedef __attribute__((ext_vector_type(4))) float f32x4;
typedef __attribute__((address_space(3))) char lds_char;

#define GLOAD_LDS16(gp, lp)                                                        \
    __builtin_amdgcn_global_load_lds(                                              \
        (const __attribute__((address_space(1))) void*)(gp),                       \
        (__attribute__((address_space(3))) void*)(lp), 16, 0, 0)

#define BAR()  asm volatile("s_barrier" ::: "memory")
#define VMW3() asm volatile("s_waitcnt vmcnt(3)" ::: "memory")
#define VMW0() asm volatile("s_waitcnt vmcnt(0)" ::: "memory")
#define LGK0() { asm volatile("s_waitcnt lgkmcnt(0)" ::: "memory");                \
                 __builtin_amdgcn_sched_barrier(0); }
#define DSR(dst, off)                                                              \
    asm volatile("ds_read_b128 %0, %1" : "=v"(dst) : "v"(lds3 + (off)))

#define RCP(x)  __builtin_amdgcn_rcpf(x)
#define EXP2(x) __builtin_amdgcn_exp2f(x)

__device__ __forceinline__ float tanh_fast(float x) {   // prepass-free; unused in GEMM
    float ax = fabsf(x);
    float e  = __expf(2.f * ax);
    float t  = 1.f - 2.f / (e + 1.f);
    return copysignf(t, x);
}
__device__ __forceinline__ unsigned int pkq4(float a, float b, float c, float d,
                                             float qs) {
    int q0 = __float2int_rn(a * qs) & 255;
    int q1 = __float2int_rn(b * qs) & 255;
    int q2 = __float2int_rn(c * qs) & 255;
    int q3 = __float2int_rn(d * qs) & 255;
    return (unsigned)q0 | ((unsigned)q1 << 8) | ((unsigned)q2 << 16)
         | ((unsigned)q3 << 24);
}

// ---------------- prepass A: per-row max + quantize + swizzled layout ----------
__global__ __launch_bounds__(256) void conv_a_q(const float* __restrict__ x,
                                                const float* __restrict__ h,
                                                char* __restrict__ Aq,
                                                float* __restrict__ As) {
    const int lane = threadIdx.x & 63;
    const int r    = blockIdx.x * 4 + (threadIdx.x >> 6);   // grid 4096
    const int k0   = lane * 16;
    const float* src = (k0 < 512) ? (x + (size_t)r * 512 + k0)
                                  : (h + (size_t)r * 512 + (k0 - 512));
    const float4* s4 = reinterpret_cast<const float4*>(src);
    float4 v0 = s4[0], v1 = s4[1], v2 = s4[2], v3 = s4[3];

    float m = fabsf(v0.x);
    m = fmaxf(m, fabsf(v0.y)); m = fmaxf(m, fabsf(v0.z)); m = fmaxf(m, fabsf(v0.w));
    m = fmaxf(m, fabsf(v1.x)); m = fmaxf(m, fabsf(v1.y)); m = fmaxf(m, fabsf(v1.z));
    m = fmaxf(m, fabsf(v1.w)); m = fmaxf(m, fabsf(v2.x)); m = fmaxf(m, fabsf(v2.y));
    m = fmaxf(m, fabsf(v2.z)); m = fmaxf(m, fabsf(v2.w)); m = fmaxf(m, fabsf(v3.x));
    m = fmaxf(m, fabsf(v3.y)); m = fmaxf(m, fabsf(v3.z)); m = fmaxf(m, fabsf(v3.w));
    #pragma unroll
    for (int off = 1; off < 64; off <<= 1)
        m = fmaxf(m, __shfl_xor(m, off));
    m = fmaxf(m, 1e-20f);
    const float qs = 127.0f / m;
    if (lane == 0) As[r] = m * (1.0f / 127.0f);

    uint4 o;
    o.x = pkq4(v0.x, v0.y, v0.z, v0.w, qs);
    o.y = pkq4(v1.x, v1.y, v1.z, v1.w, qs);
    o.z = pkq4(v2.x, v2.y, v2.z, v2.w, qs);
    o.w = pkq4(v3.x, v3.y, v3.z, v3.w, qs);

    const int t     = lane >> 2;
    const int csrc  = lane & 3;
    const int mt    = r >> 8;
    const int rl    = r & 255;
    const int kcpos = csrc ^ ((rl >> 1) & 3);
    *reinterpret_cast<uint4*>(Aq + (((size_t)(mt * 16 + t)) << 14)
                                 + rl * 64 + kcpos * 16) = o;
}

// ---------------- prepass W pass 1: per-(gate,col) max ----------------
__global__ __launch_bounds__(256) void conv_w_max(const float* __restrict__ w0,
                                                  const float* __restrict__ w1,
                                                  const float* __restrict__ w2,
                                                  const float* __restrict__ w3,
                                                  float* __restrict__ Ws) {
    const int lane = threadIdx.x & 63;
    const int idx  = blockIdx.x * 4 + (threadIdx.x >> 6);   // grid 512 -> 0..2047
    const int g    = idx >> 9;
    const int n    = idx & 511;
    const float* Wg = (g == 0) ? w0 : (g == 1) ? w1 : (g == 2) ? w2 : w3;
    float m = 0.f;
    #pragma unroll
    for (int u = 0; u < 16; ++u)
        m = fmaxf(m, fabsf(Wg[(size_t)(lane * 16 + u) * 512 + n]));
    #pragma unroll
    for (int off = 1; off < 64; off <<= 1)
        m = fmaxf(m, __shfl_xor(m, off));
    if (lane == 0) Ws[idx] = fmaxf(m, 1e-20f) * (1.0f / 127.0f);
}

// ---------------- prepass W pass 2: quantize + swizzled layout ----------------
__global__ __launch_bounds__(256) void conv_w_q(const float* __restrict__ w0,
                                                const float* __restrict__ w1,
                                                const float* __restrict__ w2,
                                                const float* __restrict__ w3,
                                                const float* __restrict__ Ws,
                                                char* __restrict__ Bq) {
    const int G  = blockIdx.x * 256 + threadIdx.x;   // grid 512 -> 131072
    const int b  = G >> 9;     // slice 0..255 = nb*16 + t
    const int p  = G & 511;
    const int nb = b >> 4;
    const int t  = b & 15;
    const int col   = p >> 2;
    const int kcpos = p & 3;
    const int kcsrc = kcpos ^ ((col >> 1) & 3);
    const int g  = col >> 5;
    const int n  = nb * 32 + (col & 31);
    const int k0 = t * 64 + kcsrc * 16;
    const float* Wg = (g == 0) ? w0 : (g == 1) ? w1 : (g == 2) ? w2 : w3;
    const float qs = 1.0f / Ws[g * 512 + n];
    float v[16];
    #pragma unroll
    for (int u = 0; u < 16; ++u) v[u] = Wg[(size_t)(k0 + u) * 512 + n];
    uint4 o;
    o.x = pkq4(v[0],  v[1],  v[2],  v[3],  qs);
    o.y = pkq4(v[4],  v[5],  v[6],  v[7],  qs);
    o.z = pkq4(v[8],  v[9],  v[10], v[11], qs);
    o.w = pkq4(v[12], v[13], v[14], v[15], qs);
    *reinterpret_cast<uint4*>(Bq + (size_t)b * 8192 + (size_t)p * 16) = o;
}

// ---------------- fused i8 GEMM: 256x128 tile, ring-3, 2 blocks/CU ----------------
__global__ __launch_bounds__(512, 4) void lstm_gemm8(
    const char* __restrict__ Aq, const char* __restrict__ Bq,
    const float* __restrict__ As, const float* __restrict__ Ws,
    const float* __restrict__ c_cur,
    const float* __restrict__ bi_p, const float* __restrict__ bf_p,
    const float* __restrict__ bo_p, const float* __restrict__ bc_p,
    float* __restrict__ h_out, float* __restrict__ c_out)
{
    extern __shared__ char smem[];
    lds_char* lds3 = (lds_char*)smem;
    const int tid  = threadIdx.x;
    const int lane = tid & 63;
    const int wid  = tid >> 6;    // 0..7
    const int wm   = wid >> 1;    // 0..3 (64-row group)
    const int wn   = wid & 1;     // 0..1 (16-h half)

    // XCD-grouped bijective mapping (r13, FETCH-verified)
    const int mt = (blockIdx.x & 7) * 8 + (blockIdx.x >> 7);
    const int nb = (blockIdx.x >> 3) & 15;

    const int ar    = lane & 15;
    const int swz   = ((lane >> 4) ^ ((ar >> 1) & 3)) << 4;
    const int aoffb = ar * 64 + swz;
    const int boffb = 16384 + (wn * 16 + ar) * 64 + swz;
    const int swl   = wid * 1024;

    const char* AqB = Aq + (((size_t)mt * 16) << 14) + (size_t)tid * 16;
    const char* BqB = Bq + (((size_t)nb * 16) << 13) + (size_t)tid * 16;

#define STAGE(t, bb) {                                                  \
        const char* ga_ = AqB + (((size_t)(t)) << 14);                  \
        const char* gb_ = BqB + (((size_t)(t)) << 13);                  \
        GLOAD_LDS16(ga_,        smem + (bb) + swl);                     \
        GLOAD_LDS16(ga_ + 8192, smem + (bb) + 8192 + swl);              \
        GLOAD_LDS16(gb_,        smem + (bb) + 16384 + swl); }

    i32x4 acc[4][4];   // [gate][m-frag]
    #pragma unroll
    for (int g = 0; g < 4; ++g)
        #pragma unroll
        for (int m = 0; m < 4; ++m)
            acc[g][m] = (i32x4){0, 0, 0, 0};

    i32x4 aFr[4], bFr[4];

    // prologue: stage K-tiles 0,1 into bufs 0,1 (6 loads in flight)
    STAGE(0, 0);
    STAGE(1, 24576);

    #pragma unroll 1
    for (int j = 0; j < 16; ++j) {
        const int buf  = (j % 3) * 24576;
        const int bufN = ((j + 2) % 3) * 24576;

        if (j < 15) { VMW3(); } else { VMW0(); }
        BAR();
        if (j < 14) STAGE(j + 2, bufN);

        #pragma unroll
        for (int mi = 0; mi < 4; ++mi)
            DSR(aFr[mi], buf + wm * 4096 + mi * 1024 + aoffb);
        #pragma unroll
        for (int g = 0; g < 4; ++g)
            DSR(bFr[g], buf + g * 2048 + boffb);

        LGK0();
        __builtin_amdgcn_s_setprio(1);
        #pragma unroll
        for (int g = 0; g < 4; ++g)
            #pragma unroll
            for (int m = 0; m < 4; ++m)
                acc[g][m] = __builtin_amdgcn_mfma_i32_16x16x64_i8(
                    aFr[m], bFr[g], acc[g][m], 0, 0, 0);
        __builtin_amdgcn_s_setprio(0);
    }

    // ---- fused LSTM epilogue: division-free, folded-constant form ----
    // sigma(x) = rcp(1 + 2^(-L x));  tanh(x) = 2 rcp(1 + 2^(-2L x)) - 1
    const float L2E = 1.442695041f;
    const int r4   = (lane >> 4) * 4;
    const int hcol = nb * 32 + wn * 16 + ar;
    // -L * per-(gate,col) dequant scales; -L * bias (2L for the tanh gate)
    const float swiL = -L2E * Ws[hcol];
    const float swfL = -L2E * Ws[512 + hcol];
    const float swoL = -L2E * Ws[1024 + hcol];
    const float swcL = -2.f * L2E * Ws[1536 + hcol];
    const float biL  = -L2E * bi_p[hcol];
    const float bfL  = -L2E * bf_p[hcol];
    const float boL  = -L2E * bo_p[hcol];
    const float bcL  = -2.f * L2E * bc_p[hcol];
    #pragma unroll
    for (int m = 0; m < 4; ++m) {
        const int rowb = mt * 256 + wm * 64 + m * 16 + r4;
        const float4 sa = *reinterpret_cast<const float4*>(As + rowb);
        const float sar[4] = {sa.x, sa.y, sa.z, sa.w};
        #pragma unroll
        for (int rr = 0; rr < 4; ++rr) {
            const size_t o = (size_t)(rowb + rr) * 512 + hcol;
            const float s = sar[rr];
            // t_g = -L * gate_g  (scale+bias folded; acc*swL first, then *s)
            float ti = fmaf((float)acc[0][m][rr] * swiL, s, biL);
            float tf = fmaf((float)acc[1][m][rr] * swfL, s, bfL);
            float to = fmaf((float)acc[2][m][rr] * swoL, s, boL);
            float tc = fmaf((float)acc[3][m][rr] * swcL, s, bcL);
            float is = RCP(1.f + EXP2(ti));
            float fs = RCP(1.f + EXP2(tf));
            float os = RCP(1.f + EXP2(to));
            float ct = fmaf(2.f, RCP(1.f + EXP2(tc)), -1.f);
            float cn = fmaf(fs, c_cur[o], is * ct);
            float th = fmaf(2.f, RCP(1.f + EXP2(cn * (-2.f * L2E))), -1.f);
            h_out[o] = os * th;
            c_out[o] = cn;
        }
    }
#undef STAGE
}

extern "C" void kernel_launch(void* const* d_in, const int* in_sizes, int n_in,
                              void* d_out, int out_size, void* d_ws, size_t ws_size,
                              hipStream_t stream) {
    const float* x   = (const float*)d_in[0];
    const float* h   = (const float*)d_in[1];
    const float* c   = (const float*)d_in[2];
    const float* W_i = (const float*)d_in[3];
    const float* b_i = (const float*)d_in[4];
    const float* W_f = (const float*)d_in[5];
    const float* b_f = (const float*)d_in[6];
    const float* W_o = (const float*)d_in[7];
    const float* b_o = (const float*)d_in[8];
    const float* W_c = (const float*)d_in[9];
    const float* b_c = (const float*)d_in[10];

    char*  Aq = (char*)d_ws;                             // 16,777,216 B
    char*  Bq = (char*)d_ws + 16777216;                  //  2,097,152 B
    float* As = (float*)((char*)d_ws + 18874368);        //     65,536 B
    float* Ws = (float*)((char*)d_ws + 18939904);        //      8,192 B

    float* h_out = (float*)d_out;
    float* c_out = h_out + (size_t)16384 * 512;

    (void)hipFuncSetAttribute(reinterpret_cast<const void*>(lstm_gemm8),
                              hipFuncAttributeMaxDynamicSharedMemorySize, 73728);

    conv_a_q<<<4096, 256, 0, stream>>>(x, h, Aq, As);
    conv_w_max<<<512, 256, 0, stream>>>(W_i, W_f, W_o, W_c, Ws);
    conv_w_q<<<512, 256, 0, stream>>>(W_i, W_f, W_o, W_c, Ws, Bq);
    lstm_gemm8<<<1024, 512, 73728, stream>>>(Aq, Bq, As, Ws, c,
                                             b_i, b_f, b_o, b_c, h_out, c_out);
}

// Round 20
// 73.201 us; speedup vs baseline: 8.6978x; 1.0457x over previous
//
#include <hip/hip_runtime.h>
#include <hip/hip_bf16.h>
#include <cstdint>

// LSTM cell, B=16384, IN=512, H=512 — fused 4-gate INT8 MFMA GEMM.
// Round 20: GEMM = r18 verbatim (proven: ring-3, vmcnt(3), 2 blocks/CU,
// XCD-grouped mapping, division-free epilogue). W-prep merged into ONE kernel
// (max+quantize from registers — W read once instead of twice, one fewer
// dispatch). r19's ring-2/3-block sync abandoned: post-timing race.

typedef __attribute__((ext_vector_type(4))) int   i32x4;
typedef __attribute__((ext_vector_type(4))) float f32x4;
typedef __attribute__((address_space(3))) char lds_char;

#define GLOAD_LDS16(gp, lp)                                                        \
    __builtin_amdgcn_global_load_lds(                                              \
        (const __attribute__((address_space(1))) void*)(gp),                       \
        (__attribute__((address_space(3))) void*)(lp), 16, 0, 0)

#define BAR()  asm volatile("s_barrier" ::: "memory")
#define VMW3() asm volatile("s_waitcnt vmcnt(3)" ::: "memory")
#define VMW0() asm volatile("s_waitcnt vmcnt(0)" ::: "memory")
#define LGK0() { asm volatile("s_waitcnt lgkmcnt(0)" ::: "memory");                \
                 __builtin_amdgcn_sched_barrier(0); }
#define DSR(dst, off)                                                              \
    asm volatile("ds_read_b128 %0, %1" : "=v"(dst) : "v"(lds3 + (off)))

#define RCP(x)  __builtin_amdgcn_rcpf(x)
#define EXP2(x) __builtin_amdgcn_exp2f(x)

__device__ __forceinline__ unsigned int pkq4(float a, float b, float c, float d,
                                             float qs) {
    int q0 = __float2int_rn(a * qs) & 255;
    int q1 = __float2int_rn(b * qs) & 255;
    int q2 = __float2int_rn(c * qs) & 255;
    int q3 = __float2int_rn(d * qs) & 255;
    return (unsigned)q0 | ((unsigned)q1 << 8) | ((unsigned)q2 << 16)
         | ((unsigned)q3 << 24);
}

// ---------------- prepass A: per-row max + quantize + swizzled layout ----------
__global__ __launch_bounds__(256) void conv_a_q(const float* __restrict__ x,
                                                const float* __restrict__ h,
                                                char* __restrict__ Aq,
                                                float* __restrict__ As) {
    const int lane = threadIdx.x & 63;
    const int r    = blockIdx.x * 4 + (threadIdx.x >> 6);   // grid 4096
    const int k0   = lane * 16;
    const float* src = (k0 < 512) ? (x + (size_t)r * 512 + k0)
                                  : (h + (size_t)r * 512 + (k0 - 512));
    const float4* s4 = reinterpret_cast<const float4*>(src);
    float4 v0 = s4[0], v1 = s4[1], v2 = s4[2], v3 = s4[3];

    float m = fabsf(v0.x);
    m = fmaxf(m, fabsf(v0.y)); m = fmaxf(m, fabsf(v0.z)); m = fmaxf(m, fabsf(v0.w));
    m = fmaxf(m, fabsf(v1.x)); m = fmaxf(m, fabsf(v1.y)); m = fmaxf(m, fabsf(v1.z));
    m = fmaxf(m, fabsf(v1.w)); m = fmaxf(m, fabsf(v2.x)); m = fmaxf(m, fabsf(v2.y));
    m = fmaxf(m, fabsf(v2.z)); m = fmaxf(m, fabsf(v2.w)); m = fmaxf(m, fabsf(v3.x));
    m = fmaxf(m, fabsf(v3.y)); m = fmaxf(m, fabsf(v3.z)); m = fmaxf(m, fabsf(v3.w));
    #pragma unroll
    for (int off = 1; off < 64; off <<= 1)
        m = fmaxf(m, __shfl_xor(m, off));
    m = fmaxf(m, 1e-20f);
    const float qs = 127.0f / m;
    if (lane == 0) As[r] = m * (1.0f / 127.0f);

    uint4 o;
    o.x = pkq4(v0.x, v0.y, v0.z, v0.w, qs);
    o.y = pkq4(v1.x, v1.y, v1.z, v1.w, qs);
    o.z = pkq4(v2.x, v2.y, v2.z, v2.w, qs);
    o.w = pkq4(v3.x, v3.y, v3.z, v3.w, qs);

    const int t     = lane >> 2;
    const int csrc  = lane & 3;
    const int mt    = r >> 8;
    const int rl    = r & 255;
    const int kcpos = csrc ^ ((rl >> 1) & 3);
    *reinterpret_cast<uint4*>(Aq + (((size_t)(mt * 16 + t)) << 14)
                                 + rl * 64 + kcpos * 16) = o;
}

// ---------------- prepass W: fused max + quantize (W read ONCE) ----------------
// One wave per (gate g, col n). Lane holds W_g[lane*16+u][n], u=0..15 — exactly
// one 16B Bq chunk (k0 = lane*16 = (lane>>2)*64 + (lane&3)*16). After the
// shfl max-reduce every lane has m; pack in-register and store.
__global__ __launch_bounds__(256) void conv_w_fused(const float* __restrict__ w0,
                                                    const float* __restrict__ w1,
                                                    const float* __restrict__ w2,
                                                    const float* __restrict__ w3,
                                                    float* __restrict__ Ws,
                                                    char* __restrict__ Bq) {
    const int lane = threadIdx.x & 63;
    const int idx  = blockIdx.x * 4 + (threadIdx.x >> 6);   // grid 512 -> 0..2047
    const int g    = idx >> 9;
    const int n    = idx & 511;
    const float* Wg = (g == 0) ? w0 : (g == 1) ? w1 : (g == 2) ? w2 : w3;

    float v[16];
    #pragma unroll
    for (int u = 0; u < 16; ++u)
        v[u] = Wg[(size_t)(lane * 16 + u) * 512 + n];

    float m = fabsf(v[0]);
    #pragma unroll
    for (int u = 1; u < 16; ++u) m = fmaxf(m, fabsf(v[u]));
    #pragma unroll
    for (int off = 1; off < 64; off <<= 1)
        m = fmaxf(m, __shfl_xor(m, off));
    m = fmaxf(m, 1e-20f);
    if (lane == 0) Ws[idx] = m * (1.0f / 127.0f);
    const float qs = 127.0f / m;

    uint4 o;
    o.x = pkq4(v[0],  v[1],  v[2],  v[3],  qs);
    o.y = pkq4(v[4],  v[5],  v[6],  v[7],  qs);
    o.z = pkq4(v[8],  v[9],  v[10], v[11], qs);
    o.w = pkq4(v[12], v[13], v[14], v[15], qs);

    const int nb    = n >> 5;
    const int col   = (g << 5) | (n & 31);
    const int t     = lane >> 2;
    const int kcpos = (lane & 3) ^ ((col >> 1) & 3);
    *reinterpret_cast<uint4*>(Bq + (size_t)(nb * 16 + t) * 8192
                                 + col * 64 + kcpos * 16) = o;
}

// ---------------- fused i8 GEMM: 256x128 tile, ring-3, 2 blocks/CU ----------------
__global__ __launch_bounds__(512, 4) void lstm_gemm8(
    const char* __restrict__ Aq, const char* __restrict__ Bq,
    const float* __restrict__ As, const float* __restrict__ Ws,
    const float* __restrict__ c_cur,
    const float* __restrict__ bi_p, const float* __restrict__ bf_p,
    const float* __restrict__ bo_p, const float* __restrict__ bc_p,
    float* __restrict__ h_out, float* __restrict__ c_out)
{
    extern __shared__ char smem[];
    lds_char* lds3 = (lds_char*)smem;
    const int tid  = threadIdx.x;
    const int lane = tid & 63;
    const int wid  = tid >> 6;    // 0..7
    const int wm   = wid >> 1;    // 0..3 (64-row group)
    const int wn   = wid & 1;     // 0..1 (16-h half)

    // XCD-grouped bijective mapping (r13, FETCH-verified)
    const int mt = (blockIdx.x & 7) * 8 + (blockIdx.x >> 7);
    const int nb = (blockIdx.x >> 3) & 15;

    const int ar    = lane & 15;
    const int swz   = ((lane >> 4) ^ ((ar >> 1) & 3)) << 4;
    const int aoffb = ar * 64 + swz;
    const int boffb = 16384 + (wn * 16 + ar) * 64 + swz;
    const int swl   = wid * 1024;

    const char* AqB = Aq + (((size_t)mt * 16) << 14) + (size_t)tid * 16;
    const char* BqB = Bq + (((size_t)nb * 16) << 13) + (size_t)tid * 16;

#define STAGE(t, bb) {                                                  \
        const char* ga_ = AqB + (((size_t)(t)) << 14);                  \
        const char* gb_ = BqB + (((size_t)(t)) << 13);                  \
        GLOAD_LDS16(ga_,        smem + (bb) + swl);                     \
        GLOAD_LDS16(ga_ + 8192, smem + (bb) + 8192 + swl);              \
        GLOAD_LDS16(gb_,        smem + (bb) + 16384 + swl); }

    i32x4 acc[4][4];   // [gate][m-frag]
    #pragma unroll
    for (int g = 0; g < 4; ++g)
        #pragma unroll
        for (int m = 0; m < 4; ++m)
            acc[g][m] = (i32x4){0, 0, 0, 0};

    i32x4 aFr[4], bFr[4];

    // prologue: stage K-tiles 0,1 into bufs 0,1 (6 loads in flight)
    STAGE(0, 0);
    STAGE(1, 24576);

    #pragma unroll 1
    for (int j = 0; j < 16; ++j) {
        const int buf  = (j % 3) * 24576;
        const int bufN = ((j + 2) % 3) * 24576;

        if (j < 15) { VMW3(); } else { VMW0(); }
        BAR();
        if (j < 14) STAGE(j + 2, bufN);

        #pragma unroll
        for (int mi = 0; mi < 4; ++mi)
            DSR(aFr[mi], buf + wm * 4096 + mi * 1024 + aoffb);
        #pragma unroll
        for (int g = 0; g < 4; ++g)
            DSR(bFr[g], buf + g * 2048 + boffb);

        LGK0();
        __builtin_amdgcn_s_setprio(1);
        #pragma unroll
        for (int g = 0; g < 4; ++g)
            #pragma unroll
            for (int m = 0; m < 4; ++m)
                acc[g][m] = __builtin_amdgcn_mfma_i32_16x16x64_i8(
                    aFr[m], bFr[g], acc[g][m], 0, 0, 0);
        __builtin_amdgcn_s_setprio(0);
    }

    // ---- fused LSTM epilogue: division-free, folded-constant form ----
    const float L2E = 1.442695041f;
    const int r4   = (lane >> 4) * 4;
    const int hcol = nb * 32 + wn * 16 + ar;
    const float swiL = -L2E * Ws[hcol];
    const float swfL = -L2E * Ws[512 + hcol];
    const float swoL = -L2E * Ws[1024 + hcol];
    const float swcL = -2.f * L2E * Ws[1536 + hcol];
    const float biL  = -L2E * bi_p[hcol];
    const float bfL  = -L2E * bf_p[hcol];
    const float boL  = -L2E * bo_p[hcol];
    const float bcL  = -2.f * L2E * bc_p[hcol];
    #pragma unroll
    for (int m = 0; m < 4; ++m) {
        const int rowb = mt * 256 + wm * 64 + m * 16 + r4;
        const float4 sa = *reinterpret_cast<const float4*>(As + rowb);
        const float sar[4] = {sa.x, sa.y, sa.z, sa.w};
        #pragma unroll
        for (int rr = 0; rr < 4; ++rr) {
            const size_t o = (size_t)(rowb + rr) * 512 + hcol;
            const float s = sar[rr];
            float ti = fmaf((float)acc[0][m][rr] * swiL, s, biL);
            float tf = fmaf((float)acc[1][m][rr] * swfL, s, bfL);
            float to = fmaf((float)acc[2][m][rr] * swoL, s, boL);
            float tc = fmaf((float)acc[3][m][rr] * swcL, s, bcL);
            float is = RCP(1.f + EXP2(ti));
            float fs = RCP(1.f + EXP2(tf));
            float os = RCP(1.f + EXP2(to));
            float ct = fmaf(2.f, RCP(1.f + EXP2(tc)), -1.f);
            float cn = fmaf(fs, c_cur[o], is * ct);
            float th = fmaf(2.f, RCP(1.f + EXP2(cn * (-2.f * L2E))), -1.f);
            h_out[o] = os * th;
            c_out[o] = cn;
        }
    }
#undef STAGE
}

extern "C" void kernel_launch(void* const* d_in, const int* in_sizes, int n_in,
                              void* d_out, int out_size, void* d_ws, size_t ws_size,
                              hipStream_t stream) {
    const float* x   = (const float*)d_in[0];
    const float* h   = (const float*)d_in[1];
    const float* c   = (const float*)d_in[2];
    const float* W_i = (const float*)d_in[3];
    const float* b_i = (const float*)d_in[4];
    const float* W_f = (const float*)d_in[5];
    const float* b_f = (const float*)d_in[6];
    const float* W_o = (const float*)d_in[7];
    const float* b_o = (const float*)d_in[8];
    const float* W_c = (const float*)d_in[9];
    const float* b_c = (const float*)d_in[10];

    char*  Aq = (char*)d_ws;                             // 16,777,216 B
    char*  Bq = (char*)d_ws + 16777216;                  //  2,097,152 B
    float* As = (float*)((char*)d_ws + 18874368);        //     65,536 B
    float* Ws = (float*)((char*)d_ws + 18939904);        //      8,192 B

    float* h_out = (float*)d_out;
    float* c_out = h_out + (size_t)16384 * 512;

    (void)hipFuncSetAttribute(reinterpret_cast<const void*>(lstm_gemm8),
                              hipFuncAttributeMaxDynamicSharedMemorySize, 73728);

    conv_a_q<<<4096, 256, 0, stream>>>(x, h, Aq, As);
    conv_w_fused<<<512, 256, 0, stream>>>(W_i, W_f, W_o, W_c, Ws, Bq);
    lstm_gemm8<<<1024, 512, 73728, stream>>>(Aq, Bq, As, Ws, c,
                                             b_i, b_f, b_o, b_c, h_out, c_out);
}